// Round 1
// baseline (1081.243 us; speedup 1.0000x reference)
//
#include <hip/hip_runtime.h>

// Problem constants
#define E_ 16
#define H_ 2048
#define I_ 1408
#define TWOI_ 2816
#define K_ 2
#define T_ 8192
#define TK_ 16384   // T_*K_

typedef unsigned short ushort_t;
typedef unsigned int uint_t;
typedef short short8 __attribute__((ext_vector_type(8)));
typedef float f32x4 __attribute__((ext_vector_type(4)));

#define AS1 __attribute__((address_space(1)))
#define AS3 __attribute__((address_space(3)))

__device__ __forceinline__ void gl2lds16(const ushort_t* g, ushort_t* l) {
    // async global->LDS, 16B per lane; LDS dest = wave-uniform base + lane*16
    __builtin_amdgcn_global_load_lds((const AS1 uint_t*)g, (AS3 uint_t*)l, 16, 0, 0);
}

__device__ __forceinline__ ushort_t f2bf(float f) {
    uint_t u = __float_as_uint(f);
    u += 0x7fffu + ((u >> 16) & 1u);   // round-to-nearest-even
    return (ushort_t)(u >> 16);
}
__device__ __forceinline__ uint_t pack2(float a, float b) {
    return (uint_t)f2bf(a) | ((uint_t)f2bf(b) << 16);
}
__device__ __forceinline__ float bflo(uint_t v) { return __uint_as_float(v << 16); }
__device__ __forceinline__ float bfhi(uint_t v) { return __uint_as_float(v & 0xffff0000u); }

// ---------------------------------------------------------------------------
// meta layout (ints): [0]=ntiles, [1..17]=offs[17], [32..191]=tile_e, [192..351]=tile_row0
// Tiles are 256 rows (matches 256^2 GEMM tile).
// ---------------------------------------------------------------------------
__global__ void routing_kernel(const int* __restrict__ idx32,
                               const float* __restrict__ wts,
                               int* __restrict__ meta,
                               int* __restrict__ token_ids,
                               int* __restrict__ row_of_slot) {
    __shared__ int s_cnt[E_], s_off[E_ + 1], s_cur[E_], s_orodd;
    const int tid = threadIdx.x;
    if (tid < E_) { s_cnt[tid] = 0; s_cur[tid] = 0; }
    if (tid == 0) s_orodd = 0;
    __syncthreads();
    // int64 vs int32 detection: if input is int64, odd 32-bit words are all 0.
    int ao = 0;
    for (int s = tid; s < TK_ / 2; s += (int)blockDim.x) ao |= idx32[2 * s + 1];
    atomicOr(&s_orodd, ao);
    __syncthreads();
    const bool is64 = (s_orodd == 0);
    for (int s = tid; s < TK_; s += (int)blockDim.x) {
        int e = is64 ? idx32[2 * s] : idx32[s];
        atomicAdd(&s_cnt[e], 1);
    }
    __syncthreads();
    if (tid == 0) {
        int acc = 0, nt = 0;
        for (int e = 0; e < E_; e++) {
            s_off[e] = acc;
            meta[1 + e] = acc;
            for (int m = 0; m < s_cnt[e]; m += 256) {
                meta[32 + nt] = e;
                meta[192 + nt] = acc + m;
                nt++;
            }
            acc += s_cnt[e];
        }
        s_off[E_] = acc;
        meta[1 + E_] = acc;
        meta[0] = nt;
    }
    __syncthreads();
    for (int s = tid; s < TK_; s += (int)blockDim.x) {
        int e = is64 ? idx32[2 * s] : idx32[s];
        int p = atomicAdd(&s_cur[e], 1);
        int r = s_off[e] + p;
        token_ids[r] = s >> 1;   // token = s / K_, K_=2
        row_of_slot[s] = r;
    }
}

// ---------------------------------------------------------------------------
// fp32 -> bf16 bulk conversion, 8 elements/thread, 16B stores
// ---------------------------------------------------------------------------
__global__ void f2bf_kernel(const float* __restrict__ src, ushort_t* __restrict__ dst, int n8) {
    int i = blockIdx.x * blockDim.x + threadIdx.x;
    const int stride = gridDim.x * blockDim.x;
    for (; i < n8; i += stride) {
        const float4* s = (const float4*)src + 2 * (size_t)i;
        float4 a = s[0], b = s[1];
        uint4 o;
        o.x = pack2(a.x, a.y);
        o.y = pack2(a.z, a.w);
        o.z = pack2(b.x, b.y);
        o.w = pack2(b.z, b.w);
        ((uint4*)dst)[i] = o;
    }
}

// ---------------------------------------------------------------------------
// w_gu fp32 -> bf16 with gate/up row interleave:
// pair-group p: dst rows [32p,32p+16) = gate rows [16p,16p+16),
//               dst rows [32p+16,32p+32) = up rows [16p,16p+16)
// => consecutive 16-col GEMM subtiles alternate gate/up with the matching
//    pair in the SAME lane -> epilogue SwiGLU is lane-local.
// ---------------------------------------------------------------------------
__global__ void f2bf_gu_kernel(const float* __restrict__ src, ushort_t* __restrict__ dst) {
    const int PER_E = TWOI_ * (H_ / 8);
    const int n8 = E_ * PER_E;
    int i = blockIdx.x * blockDim.x + threadIdx.x;
    const int stride = gridDim.x * blockDim.x;
    for (; i < n8; i += stride) {
        int e = i / PER_E;
        int rem = i % PER_E;
        int r = rem / (H_ / 8);
        int cg = rem % (H_ / 8);
        int pr;
        if (r < I_) pr = 32 * (r >> 4) + (r & 15);
        else { int r2 = r - I_; pr = 32 * (r2 >> 4) + 16 + (r2 & 15); }
        const float4* s = (const float4*)src + 2 * (size_t)i;
        float4 a = s[0], b = s[1];
        uint4 o;
        o.x = pack2(a.x, a.y);
        o.y = pack2(a.z, a.w);
        o.z = pack2(b.x, b.y);
        o.w = pack2(b.z, b.w);
        *(uint4*)(dst + ((size_t)e * TWOI_ + pr) * H_ + cg * 8) = o;
    }
}

// ---------------------------------------------------------------------------
// 256x256 MFMA GEMM, BK=64, 8 waves (2x4 of 128x64), 128 KiB double-buffered
// LDS, global_load_lds staging with both-sides XOR swizzle (st-16x32 analog:
// source 16B-chunk permute <-> swizzled ds_read_b128), 2-deep counted-vmcnt
// pipeline (stage tile t+2; s_waitcnt vmcnt(8) in steady state, never 0),
// raw s_barrier + sched_barrier(0) fences, s_setprio(1) around MFMA clusters.
// Bijective chunked XCD swizzle (m204) + grouped x-sweep for L2 locality.
// MODE 0: A gathered by token_ids; epilogue = SwiGLU(pairs) -> Hb bf16 [rows,I]
// MODE 1: A direct rows; epilogue = raw bf16 -> Y [rows, NCOLS]
// B is [E][NCOLS][KDIM] bf16 row-major (B^T form, k contiguous)
// ---------------------------------------------------------------------------
template <int NCOLS, int KDIM, int MODE>
__global__ __launch_bounds__(512, 2) void moe_gemm(
    const ushort_t* __restrict__ A, const ushort_t* __restrict__ Bw,
    const int* __restrict__ meta, const int* __restrict__ token_ids,
    ushort_t* __restrict__ Obf) {
    extern __shared__ ushort_t sh[];
    constexpr int NT = KDIM / 64;          // K-tiles of 64
    static_assert(NT % 2 == 0, "K-tile count must be even");
    constexpr int TILEE = 256 * 64;        // elems per operand per K-tile (32 KB)
    constexpr int BUFE = 2 * TILEE;        // A+B per buffer (64 KB)

    const int ny = NCOLS / 256;
    const int nx = meta[0];
    const int nwg = nx * ny;
    int flat = blockIdx.x;
    if (flat >= nwg) return;
    {   // bijective chunked XCD swizzle: consecutive logical tiles -> same XCD
        const int q = nwg >> 3, r = nwg & 7;
        const int x = flat & 7, i = flat >> 3;
        flat = (x < r ? x * (q + 1) : r * (q + 1) + (x - r) * q) + i;
    }
    const int GRP = 4;                     // x-tiles sweeping y together
    const int gid = flat / (GRP * ny), rem = flat % (GRP * ny);
    const int gx = min(GRP, nx - gid * GRP);
    const int bx = gid * GRP + rem % gx;
    const int by = rem / gx;

    const int e = meta[32 + bx];
    const int row0 = meta[192 + bx];
    const int rend = meta[2 + e];
    const int mrows = min(256, rend - row0);
    const int n0 = by * 256;
    const int tid = threadIdx.x;
    const int lane = tid & 63, wid = tid >> 6;
    const int wr = wid >> 2, wc = wid & 3;   // wave -> 128x64 output sub-tile

    // ---- staging: per K-tile, 4 A-calls + 4 B-calls per thread; each call
    // stages 64 rows x 128B across the block (wave wid: rows c*64+wid*8..+8,
    // lane l: 16B chunk).  Source col is inverse-XOR-swizzled so the linear
    // gl2lds dest yields LDS[r][j] = global(r, j ^ ((r&7)<<3)) (elems).
    const int l8 = lane >> 3;
    const int srcswz = ((lane & 7) ^ l8) << 3;   // element offset of 16B chunk
    const int ldst = wid * 512;                   // wave's elems within a call-block
    const ushort_t* Be = Bw + (size_t)e * NCOLS * KDIM;
    const ushort_t* apt[4];
    const ushort_t* bpt[4];
#pragma unroll
    for (int c = 0; c < 4; c++) {
        const int ra = c * 64 + wid * 8 + l8;
        const int rc = min(ra, mrows - 1);        // clamp: dup rows, masked at epilogue
        const long arow = (MODE == 0) ? (long)token_ids[row0 + rc] : (long)(row0 + rc);
        apt[c] = A + arow * KDIM + srcswz;
        bpt[c] = Be + (size_t)(n0 + ra) * KDIM + srcswz;
    }

    auto stage = [&](int bsel) {
        ushort_t* ab = sh + bsel * BUFE;
#pragma unroll
        for (int c = 0; c < 4; c++) {
            gl2lds16(apt[c], ab + c * 4096 + ldst);
            gl2lds16(bpt[c], ab + TILEE + c * 4096 + ldst);
            apt[c] += 64; bpt[c] += 64;
        }
    };

    f32x4 acc[8][4];
#pragma unroll
    for (int i = 0; i < 8; i++)
#pragma unroll
        for (int j = 0; j < 4; j++) acc[i][j] = (f32x4){0.f, 0.f, 0.f, 0.f};

    // fragment read constants: A row = wr*128+mt*16+fr, k-chunk = (lane>>4)*8 + ks*32,
    // read addr elem = row*64 + (kchunk ^ ((row&7)<<3)); row&7 == fr&7.
    const int fr = lane & 15;
    const int axm = (fr & 7) << 3;
    const int k0 = ((lane >> 4) * 8) ^ axm;
    const int k1 = (((lane >> 4) * 8) + 32) ^ axm;

    // prologue: stage tiles 0,1; wait tile0 (leave tile1's 8 in flight)
    stage(0);
    stage(1);
    asm volatile("s_waitcnt vmcnt(8)" ::: "memory");
    __builtin_amdgcn_sched_barrier(0);
    __builtin_amdgcn_s_barrier();
    __builtin_amdgcn_sched_barrier(0);

    auto body = [&](int bsel, int t) {
        const ushort_t* af_base = sh + bsel * BUFE + (wr * 128 + fr) * 64;
        const ushort_t* bf_base = sh + bsel * BUFE + TILEE + (wc * 64 + fr) * 64;
        short8 bfr[4][2], af[4][2];
#pragma unroll
        for (int nt = 0; nt < 4; nt++) {
            bfr[nt][0] = *(const short8*)(bf_base + nt * 1024 + k0);
            bfr[nt][1] = *(const short8*)(bf_base + nt * 1024 + k1);
        }
#pragma unroll
        for (int mt = 0; mt < 4; mt++) {
            af[mt][0] = *(const short8*)(af_base + mt * 1024 + k0);
            af[mt][1] = *(const short8*)(af_base + mt * 1024 + k1);
        }
        __builtin_amdgcn_s_setprio(1);
#pragma unroll
        for (int mt = 0; mt < 4; mt++)
#pragma unroll
            for (int nt = 0; nt < 4; nt++) {
                acc[mt][nt] = __builtin_amdgcn_mfma_f32_16x16x32_bf16(af[mt][0], bfr[nt][0], acc[mt][nt], 0, 0, 0);
                acc[mt][nt] = __builtin_amdgcn_mfma_f32_16x16x32_bf16(af[mt][1], bfr[nt][1], acc[mt][nt], 0, 0, 0);
            }
        __builtin_amdgcn_s_setprio(0);
        // second M-half fragments (reuse af storage: keeps VGPR < 256)
#pragma unroll
        for (int mt = 0; mt < 4; mt++) {
            af[mt][0] = *(const short8*)(af_base + 4096 + mt * 1024 + k0);
            af[mt][1] = *(const short8*)(af_base + 4096 + mt * 1024 + k1);
        }
        __builtin_amdgcn_sched_barrier(0);
        asm volatile("s_waitcnt lgkmcnt(0)" ::: "memory");   // all my LDS reads landed
        __builtin_amdgcn_sched_barrier(0);
        __builtin_amdgcn_s_barrier();                        // all waves done reading buf
        __builtin_amdgcn_sched_barrier(0);
        if (t + 2 < NT) stage(bsel);                         // overwrite with tile t+2
        __builtin_amdgcn_s_setprio(1);
#pragma unroll
        for (int mt = 0; mt < 4; mt++)
#pragma unroll
            for (int nt = 0; nt < 4; nt++) {
                acc[4 + mt][nt] = __builtin_amdgcn_mfma_f32_16x16x32_bf16(af[mt][0], bfr[nt][0], acc[4 + mt][nt], 0, 0, 0);
                acc[4 + mt][nt] = __builtin_amdgcn_mfma_f32_16x16x32_bf16(af[mt][1], bfr[nt][1], acc[4 + mt][nt], 0, 0, 0);
            }
        __builtin_amdgcn_s_setprio(0);
        __builtin_amdgcn_sched_barrier(0);
        if (t + 2 < NT)
            asm volatile("s_waitcnt vmcnt(8)" ::: "memory"); // tile t+1 done; t+2 in flight
        else
            asm volatile("s_waitcnt vmcnt(0)" ::: "memory"); // pipeline drain (tail)
        __builtin_amdgcn_sched_barrier(0);
        __builtin_amdgcn_s_barrier();
        __builtin_amdgcn_sched_barrier(0);
    };

#pragma unroll 1
    for (int tt = 0; tt < NT; tt += 2) {
        body(0, tt);
        body(1, tt + 1);
    }

    // epilogue: C/D layout col=lane&15, row=(lane>>4)*4+reg
    const int quad = lane >> 4, tn = lane & 15;
    if (MODE == 0) {
        // nt even = gate, nt odd = up (same lane); Hb col = (n0+wc*64)/2 + j*16 + tn
        const int hbase = ((n0 + wc * 64) >> 1) + tn;
#pragma unroll
        for (int mt = 0; mt < 8; mt++) {
#pragma unroll
            for (int reg = 0; reg < 4; reg++) {
                const int rl = wr * 128 + mt * 16 + quad * 4 + reg;
                if (rl < mrows) {
                    ushort_t* dst = Obf + (size_t)(row0 + rl) * I_ + hbase;
#pragma unroll
                    for (int j = 0; j < 2; j++) {
                        float g = acc[mt][2 * j][reg];
                        float u = acc[mt][2 * j + 1][reg];
                        float h = g / (1.f + __expf(-g)) * u;
                        dst[j * 16] = f2bf(h);
                    }
                }
            }
        }
    } else {
#pragma unroll
        for (int mt = 0; mt < 8; mt++) {
#pragma unroll
            for (int reg = 0; reg < 4; reg++) {
                const int rl = wr * 128 + mt * 16 + quad * 4 + reg;
                if (rl < mrows) {
                    ushort_t* dst = Obf + (size_t)(row0 + rl) * NCOLS + n0 + wc * 64 + tn;
#pragma unroll
                    for (int nt = 0; nt < 4; nt++) dst[nt * 16] = f2bf(acc[mt][nt][reg]);
                }
            }
        }
    }
}

// ---------------------------------------------------------------------------
// Combine: out[t,:] = sum_k wts[t,k] * Y[row_of_slot[t*K+k], :]   (fp32 out)
// ---------------------------------------------------------------------------
__global__ void combine_kernel(const ushort_t* __restrict__ Y,
                               const int* __restrict__ row_of_slot,
                               const float* __restrict__ wts,
                               float* __restrict__ out) {
    const int n8 = T_ * (H_ / 8);
    int i = blockIdx.x * blockDim.x + threadIdx.x;
    const int stride = gridDim.x * blockDim.x;
    for (; i < n8; i += stride) {
        const int t = i / (H_ / 8);
        const int c = (i % (H_ / 8)) * 8;
        const int r0 = row_of_slot[2 * t], r1 = row_of_slot[2 * t + 1];
        const float w0 = wts[2 * t], w1 = wts[2 * t + 1];
        const uint4 y0 = *(const uint4*)(Y + (size_t)r0 * H_ + c);
        const uint4 y1 = *(const uint4*)(Y + (size_t)r1 * H_ + c);
        const uint_t a[4] = {y0.x, y0.y, y0.z, y0.w};
        const uint_t b[4] = {y1.x, y1.y, y1.z, y1.w};
        float o[8];
#pragma unroll
        for (int j = 0; j < 4; j++) {
            o[2 * j]     = w0 * bflo(a[j]) + w1 * bflo(b[j]);
            o[2 * j + 1] = w0 * bfhi(a[j]) + w1 * bfhi(b[j]);
        }
        float4* dst = (float4*)(out + (size_t)t * H_ + c);
        dst[0] = make_float4(o[0], o[1], o[2], o[3]);
        dst[1] = make_float4(o[4], o[5], o[6], o[7]);
    }
}

// ---------------------------------------------------------------------------
extern "C" void kernel_launch(void* const* d_in, const int* in_sizes, int n_in,
                              void* d_out, int out_size, void* d_ws, size_t ws_size,
                              hipStream_t stream) {
    const float* hidden = (const float*)d_in[0];
    const int* topk_idx = (const int*)d_in[1];
    const float* topk_w = (const float*)d_in[2];
    const float* w_gu = (const float*)d_in[3];
    const float* w_d = (const float*)d_in[4];
    float* out = (float*)d_out;

    // workspace layout (bytes)
    char* ws = (char*)d_ws;
    int* meta = (int*)ws;                                // 4 KiB
    int* token_ids = (int*)(ws + 4096);                  // 64 KiB
    int* row_of_slot = (int*)(ws + 4096 + 65536);        // 64 KiB
    ushort_t* Xb = (ushort_t*)(ws + 135168);             // T*H bf16      = 33.6 MB
    ushort_t* Wgu = Xb + (size_t)T_ * H_;                // E*2I*H bf16   = 184.6 MB
    ushort_t* Wd = Wgu + (size_t)E_ * TWOI_ * H_;        // E*H*I bf16    = 92.3 MB
    ushort_t* Hb = Wd + (size_t)E_ * H_ * I_;            // TK*I bf16     = 46.2 MB
    ushort_t* Y = Hb + (size_t)TK_ * I_;                 // TK*H bf16     = 67.1 MB

    // allow 128 KiB dynamic LDS (HK-style; idempotent, not a stream op ->
    // graph-capture safe). Errors ignored: some ROCm versions need no opt-in.
    (void)hipFuncSetAttribute(reinterpret_cast<const void*>(moe_gemm<TWOI_, H_, 0>),
                              hipFuncAttributeMaxDynamicSharedMemorySize, 131072);
    (void)hipFuncSetAttribute(reinterpret_cast<const void*>(moe_gemm<H_, I_, 1>),
                              hipFuncAttributeMaxDynamicSharedMemorySize, 131072);

    routing_kernel<<<1, 1024, 0, stream>>>(topk_idx, topk_w, meta, token_ids, row_of_slot);

    f2bf_kernel<<<4096, 256, 0, stream>>>(hidden, Xb, (int)((size_t)T_ * H_ / 8));
    f2bf_gu_kernel<<<8192, 256, 0, stream>>>(w_gu, Wgu);
    f2bf_kernel<<<8192, 256, 0, stream>>>(w_d, Wd, (int)((size_t)E_ * H_ * I_ / 8));

    // GEMM1: [rows x H] @ Wgu^T -> SwiGLU -> Hb ; 256^2 tiles: x<=80, y=11
    moe_gemm<TWOI_, H_, 0><<<80 * 11, 512, 131072, stream>>>(
        Xb, Wgu, meta, token_ids, Hb);

    // GEMM2: [rows x I] @ Wd^T -> Y ; y = 8
    moe_gemm<H_, I_, 1><<<80 * 8, 512, 131072, stream>>>(
        Hb, Wd, meta, token_ids, Y);

    combine_kernel<<<4096, 256, 0, stream>>>(Y, row_of_slot, topk_w, out);
}